// Round 8
// baseline (204.963 us; speedup 1.0000x reference)
//
#include <hip/hip_runtime.h>

typedef _Float16 half8 __attribute__((ext_vector_type(8)));
typedef float f32x4 __attribute__((ext_vector_type(4)));

#define HH 64
#define WW 64
#define HW 4096
#define COUT 256
#define NROWS 12      // staged input rows [rowbase, rowbase+11]
#define XROW 65       // px slots per staged row
#define XS_OFF 37888  // byte offset of Xs inside smem (= 64*592 Bs bytes)

// Raw barrier: flush LDS (lgkmcnt) but do NOT drain vmcnt — staging global
// loads stay in flight across the barrier (compiler waits at their uses).
__device__ __forceinline__ void bar_sync() {
    asm volatile("s_waitcnt lgkmcnt(0)" ::: "memory");
    __builtin_amdgcn_s_barrier();
    asm volatile("" ::: "memory");
}

// ---------------------------------------------------------------------------
// Kernel 1: blend circle weights -> f16, pre-fragmented MFMA A layout.
// Thread = (tap, cg, tm, lane) emits ONE 16B fragment (tap block-uniform).
// wp[((ksg*16 + tm)*64 + lane)*8], ksg = cg*9 + tap, lane = rr | (q<<4),
// element j covers channel cg*32 + q*8 + j.
// ---------------------------------------------------------------------------
__global__ __launch_bounds__(256) void prep_weights(const float* __restrict__ weight,
                                                    _Float16* __restrict__ wp) {
    const int t = blockIdx.x * 256 + threadIdx.x;
    const int lane = t & 63;
    const int tm   = (t >> 6) & 15;
    const int cg   = (t >> 10) & 7;
    const int tap  = t >> 13;              // 0..8, block-uniform
    const int rr = lane & 15, q = lane >> 4;
    const int o  = tm * 16 + rr;
    const int c0 = cg * 32 + q * 8;
    const float* wb = weight + ((size_t)o * 256 + c0) * 9;
    const float Af = 0.70710678118654752f;
    const float Bf = 1.0f - Af;
    half8 v;
    #pragma unroll
    for (int j = 0; j < 8; ++j) {
        const float* w = wb + j * 9;
        float r;
        switch (tap) {
            case 0:  r = Af*(Af*w[0]+Bf*w[1]) + Bf*(Af*w[3]+Bf*w[4]); break;
            case 1:  r = w[1]; break;
            case 2:  r = Af*(Bf*w[1]+Af*w[2]) + Bf*(Bf*w[4]+Af*w[5]); break;
            case 3:  r = w[3]; break;
            case 4:  r = w[4]; break;
            case 5:  r = w[5]; break;
            case 6:  r = Bf*(Af*w[3]+Bf*w[4]) + Af*(Af*w[6]+Bf*w[7]); break;
            case 7:  r = w[7]; break;
            default: r = Bf*(Bf*w[4]+Af*w[5]) + Af*(Bf*w[7]+Af*w[8]); break;
        }
        v[j] = (_Float16)r;
    }
    const int ksg = cg * 9 + tap;
    *(half8*)&wp[(size_t)(((ksg * 16 + tm) << 6) | lane) << 3] = v;
}

// ---------------------------------------------------------------------------
// Kernel 2: pipelined LDS-staged bilinear-sample + implicit GEMM, f16.
// 256 blocks x 1024 thr (16 waves = 4/SIMD). Tile M=256 x N=64.
// Wave = (mg 0..3) x (ng 0..1) x (klq 0..1): acc[4][2] = 32 AGPR; klq splits
// the 9 ksteps/cg 5+4 (LDS-reduced in epilogue); ng splits the 64 px.
// Register diet for 16-wave residency (<=128 unified): 1.5 staging slots/thr,
// <=2 gather units/thr, NO A-prefetch (4 waves/SIMD hides L2 latency).
// ---------------------------------------------------------------------------
__global__ __launch_bounds__(1024, 4) void dcn_main(
        const float* __restrict__ x, const float* __restrict__ off,
        const float* __restrict__ msk, const _Float16* __restrict__ wp,
        const float* __restrict__ bias, float* __restrict__ out) {
    __shared__ char smem[65536];   // Bs[0..37887] | Xs[37888..62847]; epi: f32 scr
    char* BsB  = smem;
    const char* XsB = (const char*)smem + XS_OFF;

    const int tid  = threadIdx.x;          // 0..1023
    const int wv   = tid >> 6;             // 0..15
    const int lane = tid & 63;
    const int q    = lane >> 4, rr = lane & 15;
    const int px   = lane;                 // sampling pixel column

    const int mg  = wv & 3;
    const int ng  = (wv >> 2) & 1;
    const int klq = wv >> 3;
    const int klbeg = klq ? 5 : 0;
    const int nkl   = klq ? 4 : 5;

    const int bid = blockIdx.x;
    const int xcd = bid & 7;
    const int b   = xcd >> 1;
    const int h   = ((xcd & 1) << 5) | (bid >> 3);

    const int rowbase = min(max(h - 5, 0), HH - NROWS);
    const float* xb = x + (size_t)b * 256 * HW;

    // ---- staging slots: slotA = tid; slotB = 1024+tid for tid<512 ---------
    int SGa, GOFF_A, XA_A, SGb, GOFF_B, XA_B;
    {
        int sg = tid / 768, rem = tid - sg * 768;
        int row = rem >> 6, spx = rem & 63;
        SGa = sg;
        GOFF_A = (rowbase + row) * 64 + spx;
        XA_A = ((sg * NROWS + row) * XROW + spx) * 16;
        int slot = 1024 + tid;              // sg=1, rows 4..11 (for tid<512)
        rem = slot - 768;
        row = rem >> 6; spx = rem & 63;
        SGb = 1;
        GOFF_B = (rowbase + row) * 64 + spx;
        XA_B = ((NROWS + row) * XROW + spx) * 16;
    }
    const bool hasB = (tid < 512);

    // ---- per-thread gather-unit params, computed ONCE ---------------------
    // unit c (0..17): k=0 -> c=wv (all 16 waves); k=1 -> c=16+wv (waves 0,1).
    float W00[2], W01[2], W10[2], W11[2];
    int AY0[2], AY1[2], DXO[2], COLB[2], GP[2];
    const bool UV1 = (wv < 2);
    #pragma unroll
    for (int k = 0; k < 2; ++k) {
        if (k == 0 || UV1) {
            int c = (k == 0) ? wv : (16 + wv);
            int sg = c / 9, tap = c % 9;
            int ki = tap / 3, kj = tap - 3 * ki;
            const float* offp = off + (size_t)b * 18 * HW + h * 64 + px;
            float dy = offp[(2 * tap) * HW];
            float dx = offp[(2 * tap + 1) * HW];
            float mv = msk[(size_t)b * 9 * HW + (size_t)tap * HW + h * 64 + px];
            float py  = (float)(h - 1 + ki) + dy;
            float pxf = (float)(px - 1 + kj) + dx;
            float y0f = floorf(py), x0f = floorf(pxf);
            float ly = py - y0f, lx = pxf - x0f;
            float hy = 1.0f - ly, hx = 1.0f - lx;
            int y0 = (int)y0f, x0 = (int)x0f;
            int y1 = y0 + 1, x1 = x0 + 1;
            bool vy0 = (y0 >= 0) && (y0 < HH), vy1 = (y1 >= 0) && (y1 < HH);
            bool vx0 = (x0 >= 0) && (x0 < WW), vx1 = (x1 >= 0) && (x1 < WW);
            int cy0 = min(max(y0, 0), HH - 1), cy1 = min(max(y1, 0), HH - 1);
            int cx0 = min(max(x0, 0), WW - 1), cx1 = min(max(x1, 0), WW - 1);
            W00[k] = (vy0 && vx0) ? hy * hx * mv : 0.0f;
            W01[k] = (vy0 && vx1) ? hy * lx * mv : 0.0f;
            W10[k] = (vy1 && vx0) ? ly * hx * mv : 0.0f;
            W11[k] = (vy1 && vx1) ? ly * lx * mv : 0.0f;
            int ry0 = min(max(cy0 - rowbase, 0), NROWS - 1);
            int ry1 = min(max(cy1 - rowbase, 0), NROWS - 1);
            bool useG = (vy0 && (cy0 < rowbase || cy0 > rowbase + NROWS - 1))
                     || (vy1 && (cy1 < rowbase || cy1 > rowbase + NROWS - 1));
            AY0[k]  = ((sg * NROWS + ry0) * XROW + cx0) * 16;
            AY1[k]  = ((sg * NROWS + ry1) * XROW + cx0) * 16;
            DXO[k]  = (cx1 - cx0) * 16;
            COLB[k] = (tap * 32 + sg * 8) * 2;
            GP[k]   = cy0 | (cy1 << 6) | (cx0 << 12) | (cx1 << 18) | (sg << 24)
                    | (useG ? (1u << 31) : 0);
        }
    }

    f32x4 acc[4][2];
    #pragma unroll
    for (int i = 0; i < 4; ++i)
        #pragma unroll
        for (int n = 0; n < 2; ++n)
            acc[i][n] = (f32x4)0.0f;

    // ---- preload stage 0 staging values into regs -------------------------
    float RA[8], RB[8];
    {
        const float* pA = xb + (size_t)(SGa * 8) * HW + GOFF_A;
        #pragma unroll
        for (int j = 0; j < 8; ++j) RA[j] = pA[j * HW];
        if (hasB) {
            const float* pB = xb + (size_t)(SGb * 8) * HW + GOFF_B;
            #pragma unroll
            for (int j = 0; j < 8; ++j) RB[j] = pB[j * HW];
        }
    }

    #pragma unroll 1
    for (int s = 0; s < 16; ++s) {
        const int cg = s >> 1, half = s & 1;
        bar_sync();   // Xs(s-1) gathers done; Bs(cg-1) MFMA reads done
        // ---- write Xs from regs (lane-contiguous b128, conflict-free) -----
        {
            half8 v;
            #pragma unroll
            for (int j = 0; j < 8; ++j) v[j] = (_Float16)RA[j];
            *(half8*)(smem + XS_OFF + XA_A) = v;
            if (hasB) {
                half8 w;
                #pragma unroll
                for (int j = 0; j < 8; ++j) w[j] = (_Float16)RB[j];
                *(half8*)(smem + XS_OFF + XA_B) = w;
            }
        }
        // ---- issue next stage's global loads (stay in flight) -------------
        if (s < 15) {
            const int s1 = s + 1;
            const int cbase = (s1 >> 1) * 32 + (s1 & 1) * 16;
            const float* pA = xb + (size_t)(cbase + SGa * 8) * HW + GOFF_A;
            #pragma unroll
            for (int j = 0; j < 8; ++j) RA[j] = pA[j * HW];
            if (hasB) {
                const float* pB = xb + (size_t)(cbase + SGb * 8) * HW + GOFF_B;
                #pragma unroll
                for (int j = 0; j < 8; ++j) RB[j] = pB[j * HW];
            }
        }
        bar_sync();   // Xs ready
        // ---- gather: <=2 (c,px) units per thread, packed f16 math ---------
        #pragma unroll
        for (int k = 0; k < 2; ++k) {
            if (k == 0 || UV1) {
                half8 c00 = *(const half8*)(XsB + AY0[k]);
                half8 c01 = *(const half8*)(XsB + AY0[k] + DXO[k]);
                half8 c10 = *(const half8*)(XsB + AY1[k]);
                half8 c11 = *(const half8*)(XsB + AY1[k] + DXO[k]);
                half8 res = c00 * (_Float16)W00[k] + c01 * (_Float16)W01[k]
                          + c10 * (_Float16)W10[k] + c11 * (_Float16)W11[k];
                int gp = GP[k];
                if (gp < 0) {   // rare: valid corner outside staged rows
                    int cy0 = gp & 63, cy1 = (gp >> 6) & 63;
                    int cx0 = (gp >> 12) & 63, cx1 = (gp >> 18) & 63;
                    int sg = (gp >> 24) & 3;
                    const float* xc = xb + (size_t)(cg * 32 + half * 16 + sg * 8) * HW;
                    int i00 = cy0 * 64 + cx0, i01 = cy0 * 64 + cx1;
                    int i10 = cy1 * 64 + cx0, i11 = cy1 * 64 + cx1;
                    float w0 = W00[k], w1 = W01[k], w2 = W10[k], w3 = W11[k];
                    #pragma unroll
                    for (int j = 0; j < 8; ++j) {
                        float v = w0 * xc[i00] + w1 * xc[i01]
                                + w2 * xc[i10] + w3 * xc[i11];
                        res[j] = (_Float16)v;
                        xc += HW;
                    }
                }
                *(half8*)(BsB + px * 592 + COLB[k] + half * 32) = res;
            }
        }
        if (half) {
            bar_sync();   // Bs complete (both halves)
            // ---- MFMA: 4 m-tiles x 2 px-halves (ng), kl split 5+4 ---------
            const char* wpB = (const char*)wp;
            const char* bprow = BsB + (ng * 32 + rr) * 592;
            #pragma unroll 1
            for (int t = 0; t < nkl; ++t) {
                const int kl = klbeg + t;
                const char* ap = wpB
                    + ((size_t)((cg * 9 + kl) * 16 + mg * 4) * 64 + lane) * 16;
                half8 a0 = *(const half8*)ap;
                half8 a1 = *(const half8*)(ap + 1024);
                half8 a2 = *(const half8*)(ap + 2048);
                half8 a3 = *(const half8*)(ap + 3072);
                const int kc = (kl * 32 + q * 8) * 2;
                half8 bb0 = *(const half8*)(bprow + kc);
                half8 bb1 = *(const half8*)(bprow + 16 * 592 + kc);
                acc[0][0] = __builtin_amdgcn_mfma_f32_16x16x32_f16(a0, bb0, acc[0][0], 0, 0, 0);
                acc[1][0] = __builtin_amdgcn_mfma_f32_16x16x32_f16(a1, bb0, acc[1][0], 0, 0, 0);
                acc[2][0] = __builtin_amdgcn_mfma_f32_16x16x32_f16(a2, bb0, acc[2][0], 0, 0, 0);
                acc[3][0] = __builtin_amdgcn_mfma_f32_16x16x32_f16(a3, bb0, acc[3][0], 0, 0, 0);
                acc[0][1] = __builtin_amdgcn_mfma_f32_16x16x32_f16(a0, bb1, acc[0][1], 0, 0, 0);
                acc[1][1] = __builtin_amdgcn_mfma_f32_16x16x32_f16(a1, bb1, acc[1][1], 0, 0, 0);
                acc[2][1] = __builtin_amdgcn_mfma_f32_16x16x32_f16(a2, bb1, acc[2][1], 0, 0, 0);
                acc[3][1] = __builtin_amdgcn_mfma_f32_16x16x32_f16(a3, bb1, acc[3][1], 0, 0, 0);
            }
        }
    }

    // ---- epilogue: klq-partial reduce via LDS, then store -----------------
    // klq=1 wave (8 + ng*4 + mg) dumps acc (8 waves x 8 KB = 64 KB exactly);
    // klq=0 partner (same mg,ng) adds and stores.
    float* scr = (float*)smem;   // Bs/Xs dead now
    bar_sync();
    if (klq == 1) {
        const int base = (wv - 8) * 2048 + lane * 4;
        #pragma unroll
        for (int i = 0; i < 4; ++i)
            #pragma unroll
            for (int n = 0; n < 2; ++n)
                *(f32x4*)&scr[base + (i * 2 + n) * 256] = acc[i][n];
    }
    bar_sync();
    if (klq == 0) {
        const int base = wv * 2048 + lane * 4;
        #pragma unroll
        for (int i = 0; i < 4; ++i) {
            #pragma unroll
            for (int n = 0; n < 2; ++n) {
                f32x4 p = *(const f32x4*)&scr[base + (i * 2 + n) * 256];
                #pragma unroll
                for (int e = 0; e < 4; ++e) {
                    int m = (mg * 4 + i) * 16 + q * 4 + e;
                    out[((size_t)b * COUT + m) * HW + h * 64 + ng * 32 + n * 16 + rr]
                        = acc[i][n][e] + p[e] + bias[m];
                }
            }
        }
    }
}

extern "C" void kernel_launch(void* const* d_in, const int* in_sizes, int n_in,
                              void* d_out, int out_size, void* d_ws, size_t ws_size,
                              hipStream_t stream) {
    const float* x      = (const float*)d_in[0];   // [4,256,64,64]
    const float* off    = (const float*)d_in[1];   // [4,18,64,64]
    const float* msk    = (const float*)d_in[2];   // [4,9,64,64]
    const float* weight = (const float*)d_in[3];   // [256,256,3,3]
    const float* bias   = (const float*)d_in[4];   // [256]
    float* out = (float*)d_out;                    // [4,256,64,64]

    _Float16* wp = (_Float16*)d_ws;                // 589824 f16 = 1.18 MB

    prep_weights<<<288, 256, 0, stream>>>(weight, wp);
    dcn_main<<<256, 1024, 0, stream>>>(x, off, msk, wp, bias, out);
}